// Round 16
// baseline (165.011 us; speedup 1.0000x reference)
//
#include <hip/hip_runtime.h>
#include <hip/hip_bf16.h>
#include <math.h>

// ---------------------------------------------------------------------------
// Round 23: r22 (best: 104-108us) + producer CHAIN-HEAD latency cuts.
// r22 lesson (predicted -6, got -17us): exposed load latency on serial
// chain heads costs far more than VALU count. Two remaining chains, same
// class, loop body otherwise byte-identical to r22:
//   1. X SOFTWARE PIPELINE: per tile, X = f(idiv51 chain ~10 instr,
//      xL[row] LDS ~120cy, sSteps[k] LDS) gates ALL 32 Y1 fmas. Compute
//      tile tt+1's (X,row) during tile tt's MFMA window. +2 persistent
//      regs (Xn, rown) -- inside the 4-reg headroom (124->~126, cap 128).
//   2. w1col VIA HPART: hpart chunk0 already loads W1[n][0] and discards
//      it; store to w1col[128] LDS (free), stage w1x from LDS instead of
//      32 scattered 4B global loads (32 cache lines).
// Numerics: bit-identical (same values, earlier/different source).
// Measured dead ends (do not revisit): sync topology (119/125), 4-wave
// split-weights, L1-on-MFMA (122), consumer span cuts (120), pk_fma
// (118), asm AGPR MFMA (corruption). absmax 0.125 vs thr 0.4725.
// ---------------------------------------------------------------------------

#define B_N    16384
#define KQ     51
#define HD     128
#define IND    64
#define BLK    128               // 2 waves: producer + consumer
#define RPB    16                // b-rows per block
#define GRID   (B_N / RPB)       // 1024
#define TPB    ((RPB * KQ) / 16) // 51 tiles per block (exact)

typedef __attribute__((ext_vector_type(8))) short short8;
typedef __attribute__((ext_vector_type(4))) float f32x4;

union S8U { short8 s8; unsigned u[4]; };

__device__ __forceinline__ unsigned short f2bf(float f) {
    __hip_bfloat16 t = __float2bfloat16(f);
    return *reinterpret_cast<unsigned short*>(&t);
}

#if defined(__gfx950__) && defined(__has_builtin)
#if __has_builtin(__builtin_amdgcn_cvt_pk_bf16_f32)
#define HAVE_PK_BF16 1
#endif
#endif

__device__ __forceinline__ unsigned pk_bf16(float lo, float hi) {
#ifdef HAVE_PK_BF16
    typedef __attribute__((ext_vector_type(2))) __bf16 bfv2;
    bfv2 r = __builtin_amdgcn_cvt_pk_bf16_f32(lo, hi);
    return *reinterpret_cast<unsigned*>(&r);
#else
    return (unsigned)f2bf(lo) | ((unsigned)f2bf(hi) << 16);
#endif
}

__launch_bounds__(BLK, 2)
__global__ void umnn_fused(const float* __restrict__ x,  const float* __restrict__ h,
                           const float* __restrict__ W1, const float* __restrict__ b1,
                           const float* __restrict__ W2, const float* __restrict__ b2,
                           const float* __restrict__ W3, const float* __restrict__ b3,
                           const float* __restrict__ W4, const float* __restrict__ b4,
                           float* __restrict__ out)
{
    __shared__ __align__(16) float hpL[RPB * HD];      // 8 KB block hpart
    __shared__ __align__(16) char  y2x[2][4096];       // 8 KB Y2 double buffer
    __shared__ __align__(16) float hshT[63 * 20];      // 5 KB h^T staging
    __shared__ __align__(16) float vs4[TPB * 64];      // 12.75 KB per-lane partials
    __shared__ __align__(16) float b2f[HD], b3f[HD];   // 1 KB fp32 bias tables
    __shared__ float w1col[HD];                        // W1 x-column (free via hpart)
    __shared__ float xL[RPB];
    __shared__ float sSteps[KQ], sCcw[KQ];
    __shared__ float red2[2];

    const int tid  = threadIdx.x;
    const int w    = tid >> 6;
    const int lane = tid & 63;
    const int q    = lane >> 4;
    const int lm   = lane & 15;
    const int swz  = lm & 7;
    const int rowBase = blockIdx.x * RPB;

    // ---- CC tables (validated r4 formula) ----
    if (tid < KQ) {
        const int j = tid;
        const float pi50 = 0.06283185307179586f;
        sSteps[j] = __cosf((float)j * pi50);
        float s = 0.0f;
        for (int i = 0; i <= 50; i += 2) {
            float Wi = (i == 0) ? 1.0f : 2.0f / (1.0f - (float)(i * i));
            float lam;
            if (j == 0) lam = 0.5f;
            else {
                int mp = (i * j) % 100;
                lam = __cosf((float)mp * pi50);
                if (j == 50) lam *= 0.5f;
            }
            s += (lam * 0.04f) * Wi;
        }
        sCcw[j] = s;
    }
    // ---- fp32 bias tables ----
    if (tid < HD) {
        b2f[tid] = b2[tid];
        b3f[tid] = b3[tid];
    }
    // ---- xmax scan (x: 64 KB, cache-resident) ----
    {
        const f32x4* x4 = (const f32x4*)x;
        float mx = -1e30f;
        for (int i = tid; i < B_N / 4; i += BLK) {
            f32x4 v = x4[i];
            mx = fmaxf(fmaxf(mx, fmaxf(v[0], v[1])), fmaxf(v[2], v[3]));
        }
        #pragma unroll
        for (int d = 32; d > 0; d >>= 1) mx = fmaxf(mx, __shfl_xor(mx, d));
        if (lane == 0) red2[w] = mx;
    }
    // ---- stage h^T for this block's 16 rows; init xL ----
    for (int i = tid; i < RPB * 63; i += BLK) {
        int r = i / 63, d = i - r * 63;
        hshT[d * 20 + r] = h[rowBase * 63 + i];
    }
    if (tid < RPB) xL[tid] = x[rowBase + tid];
    __syncthreads();                                   // B1

    const float xmax = fmaxf(red2[0], red2[1]) + 10.0f;

    // ---- block hpart: thread tid = feature n, 16 row-accumulators.
    //      W1 row as 16 aligned f32x4 chunks, 1-chunk prefetch (r22).
    //      chunk0[0] = W1[n][0] -> stash to w1col (free x-column staging).
    {
        const int n = tid;
        float acc[RPB];
        const float b1v = b1[n];
        #pragma unroll
        for (int r = 0; r < RPB; ++r) acc[r] = b1v;

        auto doFMA = [&](float wv, int d) {
            const float* ht = hshT + d * 20;
            #pragma unroll
            for (int rc = 0; rc < RPB / 4; ++rc) {
                f32x4 hv = *(const f32x4*)(ht + rc * 4);
                acc[rc * 4 + 0] = fmaf(wv, hv[0], acc[rc * 4 + 0]);
                acc[rc * 4 + 1] = fmaf(wv, hv[1], acc[rc * 4 + 1]);
                acc[rc * 4 + 2] = fmaf(wv, hv[2], acc[rc * 4 + 2]);
                acc[rc * 4 + 3] = fmaf(wv, hv[3], acc[rc * 4 + 3]);
            }
        };

        const float* w1row = W1 + n * IND;             // 16B-aligned row base
        f32x4 wc = *(const f32x4*)(w1row);             // cols 0..3
        f32x4 wn = *(const f32x4*)(w1row + 4);
        w1col[n] = wc[0];                              // x-column, was discarded
        doFMA(wc[1], 0); doFMA(wc[2], 1); doFMA(wc[3], 2);
        int d = 3;
        #pragma unroll 1
        for (int j = 1; j < IND / 4; ++j) {            // chunks 1..15
            wc = wn;
            if (j + 1 < IND / 4)
                wn = *(const f32x4*)(w1row + 4 * (j + 1));  // prefetch next
            doFMA(wc[0], d); doFMA(wc[1], d + 1);
            doFMA(wc[2], d + 2); doFMA(wc[3], d + 3);
            d += 4;
        }
        #pragma unroll
        for (int r = 0; r < RPB; ++r) hpL[r * HD + n] = acc[r];
    }
    __syncthreads();                                   // B2 (hpL, w1col ready)

    // per-lane C-init byte offset into bias table: feature nt*16+q*4
    const int bIoff = q * 16;                          // + nt*64 at use site

    if (w == 0) {
        // ================= PRODUCER: layer 1 + layer 2 =================
        __builtin_amdgcn_s_setprio(0);
        float w1x[32];                                 // from LDS, not 32 scattered
        #pragma unroll                                 // global loads (r23)
        for (int kk = 0; kk < 4; ++kk)
            #pragma unroll
            for (int j = 0; j < 8; ++j)
                w1x[kk * 8 + j] = w1col[kk * 32 + q * 8 + j];

        short8 W2A[8][4];
        #pragma unroll
        for (int nt = 0; nt < 8; ++nt) {
            #pragma unroll
            for (int kk = 0; kk < 4; ++kk) {
                const float* p2 = W2 + (nt * 16 + lm) * HD + kk * 32 + q * 8;
                f32x4 v0 = *(const f32x4*)(p2);        // aligned (32B offset)
                f32x4 v1 = *(const f32x4*)(p2 + 4);
                S8U a2;
                a2.u[0] = pk_bf16(v0[0], v0[1]);
                a2.u[1] = pk_bf16(v0[2], v0[3]);
                a2.u[2] = pk_bf16(v1[0], v1[1]);
                a2.u[3] = pk_bf16(v1[2], v1[3]);
                W2A[nt][kk] = a2.s8;
            }
        }
        int wrOff[8];
        #pragma unroll
        for (int nt = 0; nt < 8; ++nt)
            wrOff[nt] = lm * 256 + (((2 * nt + (q >> 1)) ^ swz) << 4) + ((q & 1) << 3);
        const char* b2c = (const char*)b2f;

        // scalar X-prep for tile t: idiv51 chain + xL/sSteps LDS reads
        auto xcalc = [&](int t, float& Xo, int& rowo) {
            const int s = t * 16 + lm;                 // guarded: s <= 815
            const unsigned row = (unsigned)s / KQ;     // 0..15
            const int k = s - (int)row * KQ;
            const float x0 = xL[row];
            Xo = fmaf((xmax - x0) * 0.5f, sSteps[k] + 1.0f, x0);
            rowo = (int)row;
        };

        float Xc; int rowc;
        xcalc(0, Xc, rowc);                            // prologue head

        #pragma unroll 1
        for (int tt = 0; tt < TPB; ++tt) {
            // ---- layer 1: build Y1 fragment (X,row precomputed) ----
            short8 Y1[4];
            #pragma unroll
            for (int kk = 0; kk < 4; ++kk) {
                const float* hp = hpL + rowc * HD + kk * 32 + q * 8;
                f32x4 ha = *(const f32x4*)hp;
                f32x4 hb = *(const f32x4*)(hp + 4);
                S8U u;
                u.u[0] = pk_bf16(fmaxf(fmaf(Xc, w1x[kk*8+0], ha[0]), 0.f),
                                 fmaxf(fmaf(Xc, w1x[kk*8+1], ha[1]), 0.f));
                u.u[1] = pk_bf16(fmaxf(fmaf(Xc, w1x[kk*8+2], ha[2]), 0.f),
                                 fmaxf(fmaf(Xc, w1x[kk*8+3], ha[3]), 0.f));
                u.u[2] = pk_bf16(fmaxf(fmaf(Xc, w1x[kk*8+4], hb[0]), 0.f),
                                 fmaxf(fmaf(Xc, w1x[kk*8+5], hb[1]), 0.f));
                u.u[3] = pk_bf16(fmaxf(fmaf(Xc, w1x[kk*8+6], hb[2]), 0.f),
                                 fmaxf(fmaf(Xc, w1x[kk*8+7], hb[3]), 0.f));
                Y1[kk] = u.s8;
            }

            // ---- pipeline: next tile's X-prep (hides under MFMA) ----
            float Xn = 0.f; int rown = 0;
            if (tt + 1 < TPB) xcalc(tt + 1, Xn, rown);

            // ---- layer 2: C init from LDS bias table, 32 MFMA ----
            f32x4 C[8];
            #pragma unroll
            for (int nt = 0; nt < 8; ++nt)
                C[nt] = *(const f32x4*)(b2c + nt * 64 + bIoff);
            #pragma unroll
            for (int kk = 0; kk < 4; ++kk)
                #pragma unroll
                for (int nt = 0; nt < 8; ++nt)
                    C[nt] = __builtin_amdgcn_mfma_f32_16x16x32_bf16(W2A[nt][kk], Y1[kk], C[nt], 0, 0, 0);

            // ---- relu + pack + write Y2 ----
            char* d2 = y2x[tt & 1];
            #pragma unroll
            for (int nt = 0; nt < 8; ++nt) {
                unsigned lo = pk_bf16(fmaxf(C[nt][0], 0.f), fmaxf(C[nt][1], 0.f));
                unsigned hi = pk_bf16(fmaxf(C[nt][2], 0.f), fmaxf(C[nt][3], 0.f));
                *(int2*)(d2 + wrOff[nt]) = make_int2((int)lo, (int)hi);
            }
            Xc = Xn; rowc = rown;
            __syncthreads();                           // tile tt ready
        }
    } else {
        // ================= CONSUMER: layer 3 + layer 4 =================
        __builtin_amdgcn_s_setprio(1);                 // consumer is critical
        short8 W3A[8][4];
        f32x4  W4c[8];
        #pragma unroll
        for (int nt = 0; nt < 8; ++nt) {
            #pragma unroll
            for (int kk = 0; kk < 4; ++kk) {
                const float* p3 = W3 + (nt * 16 + lm) * HD + kk * 32 + q * 8;
                f32x4 v0 = *(const f32x4*)(p3);        // aligned (32B offset)
                f32x4 v1 = *(const f32x4*)(p3 + 4);
                S8U a3;
                a3.u[0] = pk_bf16(v0[0], v0[1]);
                a3.u[1] = pk_bf16(v0[2], v0[3]);
                a3.u[2] = pk_bf16(v1[0], v1[1]);
                a3.u[3] = pk_bf16(v1[2], v1[3]);
                W3A[nt][kk] = a3.s8;
            }
            W4c[nt] = *(const f32x4*)(W4 + nt * 16 + q * 4);
        }
        const float b4v = b4[0];
        int rdOff[4];
        #pragma unroll
        for (int kk = 0; kk < 4; ++kk)
            rdOff[kk] = lm * 256 + (((kk * 4 + q) ^ swz) << 4);
        const char* b3c = (const char*)b3f;

        #pragma unroll 1
        for (int tt = 0; tt < TPB; ++tt) {
            __syncthreads();                           // wait for tile tt
            const char* s2 = y2x[tt & 1];

            // chain head: Y2 reads + C-init reads, all pipelined LDS
            short8 Y2[4];
            #pragma unroll
            for (int kk = 0; kk < 4; ++kk)
                Y2[kk] = *(const short8*)(s2 + rdOff[kk]);
            f32x4 C[8];
            #pragma unroll
            for (int nt = 0; nt < 8; ++nt)
                C[nt] = *(const f32x4*)(b3c + nt * 64 + bIoff);

            #pragma unroll
            for (int kk = 0; kk < 4; ++kk)
                #pragma unroll
                for (int nt = 0; nt < 8; ++nt)
                    C[nt] = __builtin_amdgcn_mfma_f32_16x16x32_bf16(W3A[nt][kk], Y2[kk], C[nt], 0, 0, 0);

            // ---- layer 4 per-lane partial: NO shuffles, straight to LDS ----
            float p = 0.f;
            #pragma unroll
            for (int nt = 0; nt < 8; ++nt) {
                p = fmaf(fmaxf(C[nt][0], 0.f), W4c[nt][0], p);
                p = fmaf(fmaxf(C[nt][1], 0.f), W4c[nt][1], p);
                p = fmaf(fmaxf(C[nt][2], 0.f), W4c[nt][2], p);
                p = fmaf(fmaxf(C[nt][3], 0.f), W4c[nt][3], p);
            }
            vs4[tt * 64 + lane] = p;                   // conflict-free
        }

        // ---- deferred epilogue: 4-way quarter sum + elu + ccw + reduce ----
        {
            const int r   = lane >> 2;                 // row 0..15
            const int sub = lane & 3;
            float a = 0.f;
            #pragma unroll 1
            for (int j = 0; j < 13; ++j) {
                int k = sub + 4 * j;
                if (k < KQ) {
                    int s   = r * KQ + k;
                    int tt  = s >> 4;
                    int lm2 = s & 15;
                    const float* vb = vs4 + tt * 64 + lm2;
                    float y4 = vb[0] + vb[16] + vb[32] + vb[48] + b4v;
                    float f  = (y4 > 0.f) ? (y4 + 1.f) : __expf(y4);
                    a = fmaf(f, sCcw[k], a);
                }
            }
            a += __shfl_xor(a, 1);
            a += __shfl_xor(a, 2);
            if (sub == 0)
                out[rowBase + r] = a * (xmax - xL[r]) * 0.5f;
        }
    }
}

// ---------------------------------------------------------------------------
extern "C" void kernel_launch(void* const* d_in, const int* in_sizes, int n_in,
                              void* d_out, int out_size, void* d_ws, size_t ws_size,
                              hipStream_t stream)
{
    const float* x  = (const float*)d_in[0];
    const float* h  = (const float*)d_in[1];
    const float* W1 = (const float*)d_in[2];
    const float* b1 = (const float*)d_in[3];
    const float* W2 = (const float*)d_in[4];
    const float* b2 = (const float*)d_in[5];
    const float* W3 = (const float*)d_in[6];
    const float* b3 = (const float*)d_in[7];
    const float* W4 = (const float*)d_in[8];
    const float* b4 = (const float*)d_in[9];
    float* out = (float*)d_out;

    umnn_fused<<<GRID, BLK, 0, stream>>>(x, h, W1, b1, W2, b2, W3, b3,
                                         W4, b4, out);
}

// Round 17
// 162.633 us; speedup vs baseline: 1.0146x; 1.0146x over previous
//
#include <hip/hip_runtime.h>
#include <hip/hip_bf16.h>
#include <math.h>

// ---------------------------------------------------------------------------
// Round 24 (FINAL): exact revert to r22 -- the session's measured best
// (rocprof 104-108us, bench 162.3us, absmax 0.125). r23's bundled
// X-pipeline + w1col staging regressed to 109-112 (X-prep was already
// hidden by cross-wave overlap; pipelining it added overhead).
// Architecture: 2-wave producer/consumer, per-tile barrier, bf16 Y2
// handoff; vectorized+prefetched prologue load paths (the r22 win: -17us
// from removing the 63-deep dependent scalar W1 load chain in hpart and
// scalar W2/W3 fragment staging).
// Measured dead ends (13 loop-structure variants, do not revisit):
//   sync topology: pair-barriers 119, flag-ring 125
//   4-wave split-weights: 144 / spill / numerics-fail
//   L1-on-MFMA: 122 (producer serial span grows ~1:1 into phase)
//   consumer span cuts bundle: 120; pk_fma: 118 (operand-build movs)
//   asm-pinned AGPR MFMA: hazard corruption (absmax 4.9)
//   X software pipeline (+w1col): 109-112 (r23)
// Limit: latency-bound at register-capped 2 waves/SIMD -- 128-AGPR weight
// residency is irreducible (half-weight schemes still hold 128; LDS
// streaming exceeds LDS BW; fp8 weights exceed the 0.4725 error budget).
// Not a HW roofline (MfmaUtil ~20%, HBM 0.4%) -- a structure-local
// minimum; every escape path measured negative. Noise floor ~5us.
// ---------------------------------------------------------------------------

#define B_N    16384
#define KQ     51
#define HD     128
#define IND    64
#define BLK    128               // 2 waves: producer + consumer
#define RPB    16                // b-rows per block
#define GRID   (B_N / RPB)       // 1024
#define TPB    ((RPB * KQ) / 16) // 51 tiles per block (exact)

typedef __attribute__((ext_vector_type(8))) short short8;
typedef __attribute__((ext_vector_type(4))) float f32x4;

union S8U { short8 s8; unsigned u[4]; };

__device__ __forceinline__ unsigned short f2bf(float f) {
    __hip_bfloat16 t = __float2bfloat16(f);
    return *reinterpret_cast<unsigned short*>(&t);
}

#if defined(__gfx950__) && defined(__has_builtin)
#if __has_builtin(__builtin_amdgcn_cvt_pk_bf16_f32)
#define HAVE_PK_BF16 1
#endif
#endif

__device__ __forceinline__ unsigned pk_bf16(float lo, float hi) {
#ifdef HAVE_PK_BF16
    typedef __attribute__((ext_vector_type(2))) __bf16 bfv2;
    bfv2 r = __builtin_amdgcn_cvt_pk_bf16_f32(lo, hi);
    return *reinterpret_cast<unsigned*>(&r);
#else
    return (unsigned)f2bf(lo) | ((unsigned)f2bf(hi) << 16);
#endif
}

__launch_bounds__(BLK, 2)
__global__ void umnn_fused(const float* __restrict__ x,  const float* __restrict__ h,
                           const float* __restrict__ W1, const float* __restrict__ b1,
                           const float* __restrict__ W2, const float* __restrict__ b2,
                           const float* __restrict__ W3, const float* __restrict__ b3,
                           const float* __restrict__ W4, const float* __restrict__ b4,
                           float* __restrict__ out)
{
    __shared__ __align__(16) float hpL[RPB * HD];      // 8 KB block hpart
    __shared__ __align__(16) char  y2x[2][4096];       // 8 KB Y2 double buffer
    __shared__ __align__(16) float hshT[63 * 20];      // 5 KB h^T staging
    __shared__ __align__(16) float vs4[TPB * 64];      // 12.75 KB per-lane partials
    __shared__ __align__(16) float b2f[HD], b3f[HD];   // 1 KB fp32 bias tables
    __shared__ float xL[RPB];
    __shared__ float sSteps[KQ], sCcw[KQ];
    __shared__ float red2[2];

    const int tid  = threadIdx.x;
    const int w    = tid >> 6;
    const int lane = tid & 63;
    const int q    = lane >> 4;
    const int lm   = lane & 15;
    const int swz  = lm & 7;
    const int rowBase = blockIdx.x * RPB;

    // ---- CC tables (validated r4 formula) ----
    if (tid < KQ) {
        const int j = tid;
        const float pi50 = 0.06283185307179586f;
        sSteps[j] = __cosf((float)j * pi50);
        float s = 0.0f;
        for (int i = 0; i <= 50; i += 2) {
            float Wi = (i == 0) ? 1.0f : 2.0f / (1.0f - (float)(i * i));
            float lam;
            if (j == 0) lam = 0.5f;
            else {
                int mp = (i * j) % 100;
                lam = __cosf((float)mp * pi50);
                if (j == 50) lam *= 0.5f;
            }
            s += (lam * 0.04f) * Wi;
        }
        sCcw[j] = s;
    }
    // ---- fp32 bias tables ----
    if (tid < HD) {
        b2f[tid] = b2[tid];
        b3f[tid] = b3[tid];
    }
    // ---- xmax scan (x: 64 KB, cache-resident) ----
    {
        const f32x4* x4 = (const f32x4*)x;
        float mx = -1e30f;
        for (int i = tid; i < B_N / 4; i += BLK) {
            f32x4 v = x4[i];
            mx = fmaxf(fmaxf(mx, fmaxf(v[0], v[1])), fmaxf(v[2], v[3]));
        }
        #pragma unroll
        for (int d = 32; d > 0; d >>= 1) mx = fmaxf(mx, __shfl_xor(mx, d));
        if (lane == 0) red2[w] = mx;
    }
    // ---- stage h^T for this block's 16 rows; init xL ----
    for (int i = tid; i < RPB * 63; i += BLK) {
        int r = i / 63, d = i - r * 63;
        hshT[d * 20 + r] = h[rowBase * 63 + i];
    }
    if (tid < RPB) xL[tid] = x[rowBase + tid];
    __syncthreads();                                   // B1

    const float xmax = fmaxf(red2[0], red2[1]) + 10.0f;

    // ---- block hpart: thread tid = feature n, 16 row-accumulators.
    //      W1 row loaded as 16 aligned f32x4 chunks with 1-chunk prefetch
    //      (was 63 dependent scalar loads). Accum order d=0..62 unchanged.
    {
        const int n = tid;
        float acc[RPB];
        const float b1v = b1[n];
        #pragma unroll
        for (int r = 0; r < RPB; ++r) acc[r] = b1v;

        auto doFMA = [&](float wv, int d) {
            const float* ht = hshT + d * 20;
            #pragma unroll
            for (int rc = 0; rc < RPB / 4; ++rc) {
                f32x4 hv = *(const f32x4*)(ht + rc * 4);
                acc[rc * 4 + 0] = fmaf(wv, hv[0], acc[rc * 4 + 0]);
                acc[rc * 4 + 1] = fmaf(wv, hv[1], acc[rc * 4 + 1]);
                acc[rc * 4 + 2] = fmaf(wv, hv[2], acc[rc * 4 + 2]);
                acc[rc * 4 + 3] = fmaf(wv, hv[3], acc[rc * 4 + 3]);
            }
        };

        const float* w1row = W1 + n * IND;             // 16B-aligned row base
        f32x4 wc = *(const f32x4*)(w1row);             // cols 0..3 (col 0 = x-col, unused)
        f32x4 wn = *(const f32x4*)(w1row + 4);
        doFMA(wc[1], 0); doFMA(wc[2], 1); doFMA(wc[3], 2);
        int d = 3;
        #pragma unroll 1
        for (int j = 1; j < IND / 4; ++j) {            // chunks 1..15
            wc = wn;
            if (j + 1 < IND / 4)
                wn = *(const f32x4*)(w1row + 4 * (j + 1));  // prefetch next
            doFMA(wc[0], d); doFMA(wc[1], d + 1);
            doFMA(wc[2], d + 2); doFMA(wc[3], d + 3);
            d += 4;
        }
        #pragma unroll
        for (int r = 0; r < RPB; ++r) hpL[r * HD + n] = acc[r];
    }
    __syncthreads();                                   // B2 (hpL ready)

    // per-lane C-init byte offset into bias table: feature nt*16+q*4
    const int bIoff = q * 16;                          // + nt*64 at use site

    if (w == 0) {
        // ================= PRODUCER: layer 1 + layer 2 =================
        __builtin_amdgcn_s_setprio(0);
        float w1x[32];
        #pragma unroll
        for (int kk = 0; kk < 4; ++kk)
            #pragma unroll
            for (int j = 0; j < 8; ++j)
                w1x[kk * 8 + j] = W1[(kk * 32 + q * 8 + j) * IND];

        short8 W2A[8][4];
        #pragma unroll
        for (int nt = 0; nt < 8; ++nt) {
            #pragma unroll
            for (int kk = 0; kk < 4; ++kk) {
                const float* p2 = W2 + (nt * 16 + lm) * HD + kk * 32 + q * 8;
                f32x4 v0 = *(const f32x4*)(p2);        // aligned (32B offset)
                f32x4 v1 = *(const f32x4*)(p2 + 4);
                S8U a2;
                a2.u[0] = pk_bf16(v0[0], v0[1]);
                a2.u[1] = pk_bf16(v0[2], v0[3]);
                a2.u[2] = pk_bf16(v1[0], v1[1]);
                a2.u[3] = pk_bf16(v1[2], v1[3]);
                W2A[nt][kk] = a2.s8;
            }
        }
        int wrOff[8];
        #pragma unroll
        for (int nt = 0; nt < 8; ++nt)
            wrOff[nt] = lm * 256 + (((2 * nt + (q >> 1)) ^ swz) << 4) + ((q & 1) << 3);
        const char* b2c = (const char*)b2f;

        #pragma unroll 1
        for (int tt = 0; tt < TPB; ++tt) {
            // ---- layer 1: build Y1 fragment for this tile ----
            const int s    = tt * 16 + lm;             // 0..815
            const unsigned row = (unsigned)s / KQ;     // 0..15
            const int k    = s - (int)row * KQ;
            const float x0 = xL[row];
            const float X  = fmaf((xmax - x0) * 0.5f, sSteps[k] + 1.0f, x0);
            short8 Y1[4];
            #pragma unroll
            for (int kk = 0; kk < 4; ++kk) {
                const float* hp = hpL + row * HD + kk * 32 + q * 8;
                f32x4 ha = *(const f32x4*)hp;
                f32x4 hb = *(const f32x4*)(hp + 4);
                S8U u;
                u.u[0] = pk_bf16(fmaxf(fmaf(X, w1x[kk*8+0], ha[0]), 0.f),
                                 fmaxf(fmaf(X, w1x[kk*8+1], ha[1]), 0.f));
                u.u[1] = pk_bf16(fmaxf(fmaf(X, w1x[kk*8+2], ha[2]), 0.f),
                                 fmaxf(fmaf(X, w1x[kk*8+3], ha[3]), 0.f));
                u.u[2] = pk_bf16(fmaxf(fmaf(X, w1x[kk*8+4], hb[0]), 0.f),
                                 fmaxf(fmaf(X, w1x[kk*8+5], hb[1]), 0.f));
                u.u[3] = pk_bf16(fmaxf(fmaf(X, w1x[kk*8+6], hb[2]), 0.f),
                                 fmaxf(fmaf(X, w1x[kk*8+7], hb[3]), 0.f));
                Y1[kk] = u.s8;
            }

            // ---- layer 2: C init from LDS bias table, 32 MFMA ----
            f32x4 C[8];
            #pragma unroll
            for (int nt = 0; nt < 8; ++nt)
                C[nt] = *(const f32x4*)(b2c + nt * 64 + bIoff);
            #pragma unroll
            for (int kk = 0; kk < 4; ++kk)
                #pragma unroll
                for (int nt = 0; nt < 8; ++nt)
                    C[nt] = __builtin_amdgcn_mfma_f32_16x16x32_bf16(W2A[nt][kk], Y1[kk], C[nt], 0, 0, 0);

            // ---- relu + pack + write Y2 ----
            char* d2 = y2x[tt & 1];
            #pragma unroll
            for (int nt = 0; nt < 8; ++nt) {
                unsigned lo = pk_bf16(fmaxf(C[nt][0], 0.f), fmaxf(C[nt][1], 0.f));
                unsigned hi = pk_bf16(fmaxf(C[nt][2], 0.f), fmaxf(C[nt][3], 0.f));
                *(int2*)(d2 + wrOff[nt]) = make_int2((int)lo, (int)hi);
            }
            __syncthreads();                           // tile tt ready
        }
    } else {
        // ================= CONSUMER: layer 3 + layer 4 =================
        __builtin_amdgcn_s_setprio(1);                 // consumer is critical
        short8 W3A[8][4];
        f32x4  W4c[8];
        #pragma unroll
        for (int nt = 0; nt < 8; ++nt) {
            #pragma unroll
            for (int kk = 0; kk < 4; ++kk) {
                const float* p3 = W3 + (nt * 16 + lm) * HD + kk * 32 + q * 8;
                f32x4 v0 = *(const f32x4*)(p3);        // aligned (32B offset)
                f32x4 v1 = *(const f32x4*)(p3 + 4);
                S8U a3;
                a3.u[0] = pk_bf16(v0[0], v0[1]);
                a3.u[1] = pk_bf16(v0[2], v0[3]);
                a3.u[2] = pk_bf16(v1[0], v1[1]);
                a3.u[3] = pk_bf16(v1[2], v1[3]);
                W3A[nt][kk] = a3.s8;
            }
            W4c[nt] = *(const f32x4*)(W4 + nt * 16 + q * 4);
        }
        const float b4v = b4[0];
        int rdOff[4];
        #pragma unroll
        for (int kk = 0; kk < 4; ++kk)
            rdOff[kk] = lm * 256 + (((kk * 4 + q) ^ swz) << 4);
        const char* b3c = (const char*)b3f;

        #pragma unroll 1
        for (int tt = 0; tt < TPB; ++tt) {
            __syncthreads();                           // wait for tile tt
            const char* s2 = y2x[tt & 1];

            // chain head: Y2 reads + C-init reads, all pipelined LDS
            short8 Y2[4];
            #pragma unroll
            for (int kk = 0; kk < 4; ++kk)
                Y2[kk] = *(const short8*)(s2 + rdOff[kk]);
            f32x4 C[8];
            #pragma unroll
            for (int nt = 0; nt < 8; ++nt)
                C[nt] = *(const f32x4*)(b3c + nt * 64 + bIoff);

            #pragma unroll
            for (int kk = 0; kk < 4; ++kk)
                #pragma unroll
                for (int nt = 0; nt < 8; ++nt)
                    C[nt] = __builtin_amdgcn_mfma_f32_16x16x32_bf16(W3A[nt][kk], Y2[kk], C[nt], 0, 0, 0);

            // ---- layer 4 per-lane partial: NO shuffles, straight to LDS ----
            float p = 0.f;
            #pragma unroll
            for (int nt = 0; nt < 8; ++nt) {
                p = fmaf(fmaxf(C[nt][0], 0.f), W4c[nt][0], p);
                p = fmaf(fmaxf(C[nt][1], 0.f), W4c[nt][1], p);
                p = fmaf(fmaxf(C[nt][2], 0.f), W4c[nt][2], p);
                p = fmaf(fmaxf(C[nt][3], 0.f), W4c[nt][3], p);
            }
            vs4[tt * 64 + lane] = p;                   // conflict-free
        }

        // ---- deferred epilogue: 4-way quarter sum + elu + ccw + reduce ----
        {
            const int r   = lane >> 2;                 // row 0..15
            const int sub = lane & 3;
            float a = 0.f;
            #pragma unroll 1
            for (int j = 0; j < 13; ++j) {
                int k = sub + 4 * j;
                if (k < KQ) {
                    int s   = r * KQ + k;
                    int tt  = s >> 4;
                    int lm2 = s & 15;
                    const float* vb = vs4 + tt * 64 + lm2;
                    float y4 = vb[0] + vb[16] + vb[32] + vb[48] + b4v;
                    float f  = (y4 > 0.f) ? (y4 + 1.f) : __expf(y4);
                    a = fmaf(f, sCcw[k], a);
                }
            }
            a += __shfl_xor(a, 1);
            a += __shfl_xor(a, 2);
            if (sub == 0)
                out[rowBase + r] = a * (xmax - xL[r]) * 0.5f;
        }
    }
}

// ---------------------------------------------------------------------------
extern "C" void kernel_launch(void* const* d_in, const int* in_sizes, int n_in,
                              void* d_out, int out_size, void* d_ws, size_t ws_size,
                              hipStream_t stream)
{
    const float* x  = (const float*)d_in[0];
    const float* h  = (const float*)d_in[1];
    const float* W1 = (const float*)d_in[2];
    const float* b1 = (const float*)d_in[3];
    const float* W2 = (const float*)d_in[4];
    const float* b2 = (const float*)d_in[5];
    const float* W3 = (const float*)d_in[6];
    const float* b3 = (const float*)d_in[7];
    const float* W4 = (const float*)d_in[8];
    const float* b4 = (const float*)d_in[9];
    float* out = (float*)d_out;

    umnn_fused<<<GRID, BLK, 0, stream>>>(x, h, W1, b1, W2, b2, W3, b3,
                                         W4, b4, out);
}